// Round 9
// baseline (293.754 us; speedup 1.0000x reference)
//
#include <hip/hip_runtime.h>

#define N1 16384
#define N2 4096
#define CC 128
#define KIN 384
#define HID 256

typedef unsigned short u16;
typedef unsigned int u32;

typedef _Float16 v8h __attribute__((ext_vector_type(8)));
typedef float v4f __attribute__((ext_vector_type(4)));

// ---------- workspace layout (bytes) ----------
// W0h  fp16 256x384           @ 0        (196608)
// W1h  fp16 256x256           @ 196608   (131072)
// sst  fp32 s0,t0,s1,t1 x256  @ 327680   (4096)
// xyz2q float4 B*N2           @ 331776   (262144)
// idx3 int B*N1*3             @ 593920   (786432)
// w3   fp32 B*N1*3            @ 1380352  (786432)
// p2t  fp32 B*N2*C            @ 2166784  (8388608)
// total = 10555392

__device__ __forceinline__ u16 f2h(float f) {
    _Float16 h = (_Float16)f;
    return __builtin_bit_cast(u16, h);
}

// =====================================================================
// Fused prep + transpose (proven R5, verbatim).
// R8 lesson: standalone cost is only ~7us (PT + gap = 6.7 by R5/R8
// algebra); in-grid fusion behind knn cannot overlap (knn fills all
// 2048 block slots) and just serializes a 16us tail. Keep separate.
// =====================================================================
__global__ __launch_bounds__(256) void prep_transpose_kernel(
    const float* __restrict__ w0, const float* __restrict__ w1,
    const float* __restrict__ b0, const float* __restrict__ g0, const float* __restrict__ be0,
    const float* __restrict__ m0, const float* __restrict__ v0,
    const float* __restrict__ b1, const float* __restrict__ g1, const float* __restrict__ be1,
    const float* __restrict__ m1, const float* __restrict__ v1,
    const float* __restrict__ xyz2, const float* __restrict__ points2,
    u16* __restrict__ W0h, u16* __restrict__ W1h,
    float* __restrict__ sst, float4* __restrict__ xyz2q,
    float* __restrict__ p2t)
{
    __shared__ float tile[64][129];   // 33024 B (transpose blocks only)
    int tid = threadIdx.x;

    if (blockIdx.x < 256) {
        int bid = blockIdx.x;
        int n20 = (bid & 63) * 64;
        int b   = bid >> 6;

        int jr = tid & 63, cr = tid >> 6;
#pragma unroll 8
        for (int it = 0; it < 32; ++it) {
            int ch = it * 4 + cr;
            tile[jr][ch] = points2[((size_t)b * CC + ch) * N2 + n20 + jr];
        }
        __syncthreads();

        int cw = tid & 127, jw0 = tid >> 7;
#pragma unroll 8
        for (int it = 0; it < 32; ++it) {
            int j = it * 2 + jw0;
            p2t[((size_t)b * N2 + n20 + j) * CC + cw] = tile[j][cw];
        }
        return;
    }

    int id = (blockIdx.x - 256) * 256 + tid;
    if (id < 98304) {
        W0h[id] = f2h(w0[id]);
    } else if (id < 163840) {
        int t = id - 98304;
        W1h[t] = f2h(w1[t]);
    } else if (id < 164352) {
        int t = id - 163840;
        int o = t & 255;
        if (t < 256) {
            float s = g0[o] * rsqrtf(v0[o] + 1e-5f);
            sst[o]       = s;
            sst[256 + o] = (b0[o] - m0[o]) * s + be0[o];
        } else {
            float s = g1[o] * rsqrtf(v1[o] + 1e-5f);
            sst[512 + o] = s;
            sst[768 + o] = (b1[o] - m1[o]) * s + be1[o];
        }
    } else if (id < 180736) {
        int t = id - 164352;  // b*N2+n
        float x = xyz2[(size_t)t * 3 + 0];
        float y = xyz2[(size_t)t * 3 + 1];
        float z = xyz2[(size_t)t * 3 + 2];
        xyz2q[t] = make_float4(x, y, z, fmaf(x, x, fmaf(y, y, z * z)));
    }
}

// =====================================================================
// 3-NN + inverse-distance weights (PROVEN 121us kernel, verbatim).
// VALU-issue floor for this algorithm (R6: per-pair cost scales with
// queries/thread; R7: half-grid split costs +12us occupancy).
// =====================================================================
#define BINS(t, cand, D0, D1, D2, I0, I1, I2) do {                    \
    bool c0 = (t) < (D0);                                             \
    bool c1 = (t) < (D1);                                             \
    bool c2 = (t) < (D2);                                             \
    I2 = c1 ? (I1) : (c2 ? (cand) : (I2));   /* old I1 */             \
    I1 = c0 ? (I0) : (c1 ? (cand) : (I1));   /* old I0 */             \
    I0 = c0 ? (cand) : (I0);                                          \
    D2 = __builtin_amdgcn_fmed3f((D1), (t), (D2));  /* old D1 */      \
    D1 = __builtin_amdgcn_fmed3f((D0), (t), (D1));  /* old D0 */      \
    D0 = fminf((t), (D0));                                            \
} while (0)

#define INS3LEX(t, j, D0, D1, D2, I0, I1, I2) do {                    \
    bool lt2 = (t) < (D2) || ((t) == (D2) && (j) < (I2));             \
    bool lt1 = (t) < (D1) || ((t) == (D1) && (j) < (I1));             \
    bool lt0 = (t) < (D0) || ((t) == (D0) && (j) < (I0));             \
    if (lt2) {                                                        \
        if (lt1) {                                                    \
            D2 = (D1); I2 = (I1);                                     \
            if (lt0) { D1 = (D0); I1 = (I0); D0 = (t); I0 = (j); }    \
            else     { D1 = (t); I1 = (j); }                          \
        } else { D2 = (t); I2 = (j); }                                \
    }                                                                 \
} while (0)

#define MERGE_STEP(st, D0, D1, D2, I0, I1, I2) do {                   \
    float e0 = __shfl_xor((D0), (st), 64);                            \
    float e1 = __shfl_xor((D1), (st), 64);                            \
    float e2 = __shfl_xor((D2), (st), 64);                            \
    int   j0 = __shfl_xor((I0), (st), 64);                            \
    int   j1 = __shfl_xor((I1), (st), 64);                            \
    int   j2 = __shfl_xor((I2), (st), 64);                            \
    INS3LEX(e0, j0, D0, D1, D2, I0, I1, I2);                          \
    INS3LEX(e1, j1, D0, D1, D2, I0, I1, I2);                          \
    INS3LEX(e2, j2, D0, D1, D2, I0, I1, I2);                          \
} while (0)

#define KNN_OUT(Q, D0, D1, D2, I0, I1, I2, PP) do {                   \
    float r0 = 1.f / ((D0) + (PP));                                   \
    float r1 = 1.f / ((D1) + (PP));                                   \
    float r2 = 1.f / ((D2) + (PP));                                   \
    float inv = 1.f / (r0 + r1 + r2);                                 \
    size_t o3 = ((size_t)b * N1 + p0 + (Q)) * 3;                      \
    idx3[o3]     = (I0);                                              \
    idx3[o3 + 1] = (I1);                                              \
    idx3[o3 + 2] = (I2);                                              \
    w3[o3]     = r0 * inv;                                            \
    w3[o3 + 1] = r1 * inv;                                            \
    w3[o3 + 2] = r2 * inv;                                            \
} while (0)

__global__ __launch_bounds__(256)
__attribute__((amdgpu_waves_per_eu(8, 8)))
void knn_kernel(
    const float* __restrict__ xyz1, const float4* __restrict__ xyz2q,
    int* __restrict__ idx3, float* __restrict__ w3)
{
    __shared__ float4 slds[1024];   // 16384 B

    int tid = threadIdx.x;
    int b   = blockIdx.y;
    int n0  = blockIdx.x * 32;

    int s  = tid & 15;
    int g  = tid >> 4;
    int p0 = n0 + g * 2;

    size_t pb = ((size_t)b * N1 + p0) * 3;
    float x0 = xyz1[pb + 0], y0 = xyz1[pb + 1], z0 = xyz1[pb + 2];
    float x1 = xyz1[pb + 3], y1 = xyz1[pb + 4], z1 = xyz1[pb + 5];
    float ax0 = -2.f * x0, ay0 = -2.f * y0, az0 = -2.f * z0;
    float ax1 = -2.f * x1, ay1 = -2.f * y1, az1 = -2.f * z1;
    float pp0 = fmaf(x0, x0, fmaf(y0, y0, z0 * z0));
    float pp1 = fmaf(x1, x1, fmaf(y1, y1, z1 * z1));

    float da0 = 1e30f, da1 = 1e30f, da2 = 1e30f;
    float db0 = 1e30f, db1 = 1e30f, db2 = 1e30f;
    int   ia0 = 0, ia1 = 0, ia2 = 0;
    int   ib0 = 0, ib1 = 0, ib2 = 0;

#pragma unroll
    for (int stage = 0; stage < 4; ++stage) {
        int base = stage * 1024;
#pragma unroll
        for (int i = 0; i < 4; ++i)
            slds[tid + i * 256] = xyz2q[(size_t)b * N2 + base + tid + i * 256];
        __syncthreads();

#pragma unroll 4
        for (int k = 0; k < 64; ++k) {
            int c = s + (k << 4);
            float4 v = slds[c];
            int cand = base + c;
            float t0 = fmaf(ax0, v.x, fmaf(ay0, v.y, fmaf(az0, v.z, v.w)));
            float t1 = fmaf(ax1, v.x, fmaf(ay1, v.y, fmaf(az1, v.z, v.w)));
            BINS(t0, cand, da0, da1, da2, ia0, ia1, ia2);
            BINS(t1, cand, db0, db1, db2, ib0, ib1, ib2);
        }
        __syncthreads();
    }

#pragma unroll
    for (int st = 1; st <= 8; st <<= 1) {
        MERGE_STEP(st, da0, da1, da2, ia0, ia1, ia2);
        MERGE_STEP(st, db0, db1, db2, ib0, ib1, ib2);
    }

    if (s == 0) {
        KNN_OUT(0, da0, da1, da2, ia0, ia1, ia2, pp0);
        KNN_OUT(1, db0, db1, db2, ib0, ib1, ib2, pp1);
    }
}

// =====================================================================
// Fused interpolate + concat + MLP(384->256->256, BN+ReLU) + channel max
// 64-POINT TILE, 4-WAVE (256-thr) blocks, 64 out-ch per wave (ot=4).
// R8 accounting: mlp ~60us; largest component is redundant LDS B-reads
// (R5: all 8 waves read the full 48KB x-tile -> 655KB ds_read/block).
// 4 waves x 64ch halves that redundancy and doubles MFMA per bf read.
// Weight traffic unchanged (same 1024 blocks). LDS 51.7KB x 3 = 155KB
// -> 3 blocks/CU via __launch_bounds__(256,3) (VGPR cap 170, est ~130).
// Mapping = cross of proven structures: R0's ot=4 channel map x R5's
// pt=4 point map; swizzle invariant p&7 == ml&7 holds for all pt.
// =====================================================================
__global__ __launch_bounds__(256, 3)
void mlp_kernel(
    const float* __restrict__ points1, const float* __restrict__ pointsb1,
    const float4* __restrict__ p2t4,
    const int* __restrict__ idx3, const float* __restrict__ w3,
    const uint4* __restrict__ W0v, const uint4* __restrict__ W1v,
    const float* __restrict__ sst, float* __restrict__ out)
{
    __shared__ __align__(16) u16 sx[64 * KIN];   // 49152 B
    __shared__ float sred[4][64];                 // 1024 B
    __shared__ int   s_idx[192];
    __shared__ float s_w[192];

    int tid = threadIdx.x;
    int b   = blockIdx.y;
    int n0  = blockIdx.x * 64;

    if (tid < 192) {
        size_t gi = ((size_t)b * N1 + n0) * 3 + tid;
        s_idx[tid] = idx3[gi];
        s_w[tid]   = w3[gi];
    }

    // ---- stage x rows 0..127 (points1) + 256..383 (points_b1) ----
    int pL  = tid & 63;              // point 0..63
    int cg4 = (tid >> 6) * 4;        // row-quad base 0,4,8,12
#pragma unroll
    for (int k = 0; k < 8; ++k) {
        int r4 = cg4 + 16 * k;       // rows 0..124 step 4
        size_t base = ((size_t)b * CC + r4) * N1 + n0 + pL;
        float a0 = points1[base];
        float a1 = points1[base + (size_t)N1];
        float a2 = points1[base + (size_t)2 * N1];
        float a3 = points1[base + (size_t)3 * N1];
        u32 lo = f2h(a0) | ((u32)f2h(a1) << 16);
        u32 hi = f2h(a2) | ((u32)f2h(a3) << 16);
        int chunk = (r4 >> 3) ^ (pL & 7);
        *(uint2*)&sx[pL * KIN + chunk * 8 + (r4 & 7)] = make_uint2(lo, hi);
    }
#pragma unroll
    for (int k = 0; k < 8; ++k) {
        int r4 = cg4 + 16 * k;
        int k4 = 256 + r4;
        size_t base = ((size_t)b * CC + r4) * N1 + n0 + pL;
        float a0 = pointsb1[base];
        float a1 = pointsb1[base + (size_t)N1];
        float a2 = pointsb1[base + (size_t)2 * N1];
        float a3 = pointsb1[base + (size_t)3 * N1];
        u32 lo = f2h(a0) | ((u32)f2h(a1) << 16);
        u32 hi = f2h(a2) | ((u32)f2h(a3) << 16);
        int chunk = (k4 >> 3) ^ (pL & 7);
        *(uint2*)&sx[pL * KIN + chunk * 8 + (k4 & 7)] = make_uint2(lo, hi);
    }
    __syncthreads();   // s_idx/s_w visible for gather

    // ---- stage x rows 128..255: 3-NN interpolation from p2t rows ----
    int c4  = tid & 31;              // channel-quad 0..31
    int pg  = tid >> 5;              // 0..7
    int k4g = 128 + c4 * 4;
#pragma unroll
    for (int k = 0; k < 8; ++k) {
        int p = pg + 8 * k;          // point 0..63
        float w0w = s_w[p * 3 + 0], w1w = s_w[p * 3 + 1], w2w = s_w[p * 3 + 2];
        float4 f0 = p2t4[((size_t)b * N2 + s_idx[p * 3 + 0]) * 32 + c4];
        float4 f1 = p2t4[((size_t)b * N2 + s_idx[p * 3 + 1]) * 32 + c4];
        float4 f2 = p2t4[((size_t)b * N2 + s_idx[p * 3 + 2]) * 32 + c4];
        float e0 = fmaf(w0w, f0.x, fmaf(w1w, f1.x, w2w * f2.x));
        float e1 = fmaf(w0w, f0.y, fmaf(w1w, f1.y, w2w * f2.y));
        float e2 = fmaf(w0w, f0.z, fmaf(w1w, f1.z, w2w * f2.z));
        float e3 = fmaf(w0w, f0.w, fmaf(w1w, f1.w, w2w * f2.w));
        u32 lo = f2h(e0) | ((u32)f2h(e1) << 16);
        u32 hi = f2h(e2) | ((u32)f2h(e3) << 16);
        int chunk = (k4g >> 3) ^ (p & 7);
        *(uint2*)&sx[p * KIN + chunk * 8 + (k4g & 7)] = make_uint2(lo, hi);
    }
    __syncthreads();

    int lane = tid & 63, w = tid >> 6;      // wave w in 0..3: o in [w*64, w*64+64)
    int ml = lane & 15, ql = lane >> 4;     // frag row/col, quad
    int px7 = ml & 7;                       // == p&7 for all pt (p=pt*16+ml)

    // ---------------- GEMM1: h1 = W0 @ x ----------------
    v4f acc1[4][4];
#pragma unroll
    for (int ot = 0; ot < 4; ++ot)
        for (int pt = 0; pt < 4; ++pt)
            acc1[ot][pt] = (v4f){0.f, 0.f, 0.f, 0.f};

#pragma unroll
    for (int s = 0; s < 12; ++s) {
        int kc = s * 4 + ql;
        int pc = (kc ^ px7) * 8;
        v8h bf0 = __builtin_bit_cast(v8h, *(const uint4*)&sx[ml * KIN + pc]);
        v8h bf1 = __builtin_bit_cast(v8h, *(const uint4*)&sx[(16 + ml) * KIN + pc]);
        v8h bf2 = __builtin_bit_cast(v8h, *(const uint4*)&sx[(32 + ml) * KIN + pc]);
        v8h bf3 = __builtin_bit_cast(v8h, *(const uint4*)&sx[(48 + ml) * KIN + pc]);
#pragma unroll
        for (int ot = 0; ot < 4; ++ot) {
            int o = w * 64 + ot * 16 + ml;
            v8h af = __builtin_bit_cast(v8h, W0v[o * 48 + kc]);
            acc1[ot][0] = __builtin_amdgcn_mfma_f32_16x16x32_f16(af, bf0, acc1[ot][0], 0, 0, 0);
            acc1[ot][1] = __builtin_amdgcn_mfma_f32_16x16x32_f16(af, bf1, acc1[ot][1], 0, 0, 0);
            acc1[ot][2] = __builtin_amdgcn_mfma_f32_16x16x32_f16(af, bf2, acc1[ot][2], 0, 0, 0);
            acc1[ot][3] = __builtin_amdgcn_mfma_f32_16x16x32_f16(af, bf3, acc1[ot][3], 0, 0, 0);
        }
    }
    __syncthreads();   // all x reads done before h1 overlays sx

    // epilogue 1: BN+ReLU -> fp16 h1[p][o] (row stride 256, swizzled)
    const float* s0v = sst;
    const float* t0v = sst + 256;
#pragma unroll
    for (int ot = 0; ot < 4; ++ot) {
        int o0 = w * 64 + ot * 16 + ql * 4;
        float sc0 = s0v[o0], sc1 = s0v[o0 + 1], sc2 = s0v[o0 + 2], sc3 = s0v[o0 + 3];
        float sh0 = t0v[o0], sh1 = t0v[o0 + 1], sh2 = t0v[o0 + 2], sh3 = t0v[o0 + 3];
        int chunk = ((o0 >> 3) ^ px7);
#pragma unroll
        for (int pt = 0; pt < 4; ++pt) {
            int p = pt * 16 + ml;
            float z0 = fmaxf(fmaf(acc1[ot][pt][0], sc0, sh0), 0.f);
            float z1 = fmaxf(fmaf(acc1[ot][pt][1], sc1, sh1), 0.f);
            float z2 = fmaxf(fmaf(acc1[ot][pt][2], sc2, sh2), 0.f);
            float z3 = fmaxf(fmaf(acc1[ot][pt][3], sc3, sh3), 0.f);
            u32 lo = f2h(z0) | ((u32)f2h(z1) << 16);
            u32 hi = f2h(z2) | ((u32)f2h(z3) << 16);
            *(uint2*)&sx[p * HID + chunk * 8 + (o0 & 7)] = make_uint2(lo, hi);
        }
    }
    __syncthreads();

    // ---------------- GEMM2: h2 = W1 @ h1 ----------------
    v4f acc2[4][4];
#pragma unroll
    for (int ot = 0; ot < 4; ++ot)
        for (int pt = 0; pt < 4; ++pt)
            acc2[ot][pt] = (v4f){0.f, 0.f, 0.f, 0.f};

#pragma unroll
    for (int s = 0; s < 8; ++s) {
        int kc = s * 4 + ql;
        int pc = (kc ^ px7) * 8;
        v8h bf0 = __builtin_bit_cast(v8h, *(const uint4*)&sx[ml * HID + pc]);
        v8h bf1 = __builtin_bit_cast(v8h, *(const uint4*)&sx[(16 + ml) * HID + pc]);
        v8h bf2 = __builtin_bit_cast(v8h, *(const uint4*)&sx[(32 + ml) * HID + pc]);
        v8h bf3 = __builtin_bit_cast(v8h, *(const uint4*)&sx[(48 + ml) * HID + pc]);
#pragma unroll
        for (int ot = 0; ot < 4; ++ot) {
            int o = w * 64 + ot * 16 + ml;
            v8h af = __builtin_bit_cast(v8h, W1v[o * 32 + kc]);
            acc2[ot][0] = __builtin_amdgcn_mfma_f32_16x16x32_f16(af, bf0, acc2[ot][0], 0, 0, 0);
            acc2[ot][1] = __builtin_amdgcn_mfma_f32_16x16x32_f16(af, bf1, acc2[ot][1], 0, 0, 0);
            acc2[ot][2] = __builtin_amdgcn_mfma_f32_16x16x32_f16(af, bf2, acc2[ot][2], 0, 0, 0);
            acc2[ot][3] = __builtin_amdgcn_mfma_f32_16x16x32_f16(af, bf3, acc2[ot][3], 0, 0, 0);
        }
    }

    // epilogue 2: BN + ReLU + channel max over this wave's 64 o
    const float* s1v = sst + 512;
    const float* t1v = sst + 768;
    float mx0 = 0.f, mx1 = 0.f, mx2 = 0.f, mx3 = 0.f;   // relu floor = 0
#pragma unroll
    for (int ot = 0; ot < 4; ++ot) {
        int o0 = w * 64 + ot * 16 + ql * 4;
#pragma unroll
        for (int r = 0; r < 4; ++r) {
            float sc = s1v[o0 + r], sh = t1v[o0 + r];
            mx0 = fmaxf(mx0, fmaf(acc2[ot][0][r], sc, sh));
            mx1 = fmaxf(mx1, fmaf(acc2[ot][1][r], sc, sh));
            mx2 = fmaxf(mx2, fmaf(acc2[ot][2][r], sc, sh));
            mx3 = fmaxf(mx3, fmaf(acc2[ot][3][r], sc, sh));
        }
    }
    mx0 = fmaxf(mx0, __shfl_xor(mx0, 16, 64));
    mx0 = fmaxf(mx0, __shfl_xor(mx0, 32, 64));
    mx1 = fmaxf(mx1, __shfl_xor(mx1, 16, 64));
    mx1 = fmaxf(mx1, __shfl_xor(mx1, 32, 64));
    mx2 = fmaxf(mx2, __shfl_xor(mx2, 16, 64));
    mx2 = fmaxf(mx2, __shfl_xor(mx2, 32, 64));
    mx3 = fmaxf(mx3, __shfl_xor(mx3, 16, 64));
    mx3 = fmaxf(mx3, __shfl_xor(mx3, 32, 64));
    if (lane < 16) {
        sred[w][ml]      = mx0;
        sred[w][16 + ml] = mx1;
        sred[w][32 + ml] = mx2;
        sred[w][48 + ml] = mx3;
    }
    __syncthreads();
    if (tid < 64) {
        float m = fmaxf(fmaxf(sred[0][tid], sred[1][tid]),
                        fmaxf(sred[2][tid], sred[3][tid]));
        out[(size_t)b * N1 + n0 + tid] = m;
    }
}

// =====================================================================
extern "C" void kernel_launch(void* const* d_in, const int* in_sizes, int n_in,
                              void* d_out, int out_size, void* d_ws, size_t ws_size,
                              hipStream_t stream)
{
    const float* xyz1     = (const float*)d_in[0];
    const float* xyz2     = (const float*)d_in[1];
    const float* points2  = (const float*)d_in[2];
    const float* points1  = (const float*)d_in[3];
    const float* pointsb1 = (const float*)d_in[4];
    const float* w0   = (const float*)d_in[5];
    const float* b0   = (const float*)d_in[6];
    const float* g0   = (const float*)d_in[7];
    const float* be0  = (const float*)d_in[8];
    const float* m0   = (const float*)d_in[9];
    const float* v0   = (const float*)d_in[10];
    const float* w1   = (const float*)d_in[11];
    const float* b1   = (const float*)d_in[12];
    const float* g1   = (const float*)d_in[13];
    const float* be1  = (const float*)d_in[14];
    const float* m1   = (const float*)d_in[15];
    const float* v1   = (const float*)d_in[16];
    float* out = (float*)d_out;

    char* ws = (char*)d_ws;
    u16*    W0h   = (u16*)(ws + 0);
    u16*    W1h   = (u16*)(ws + 196608);
    float*  sst   = (float*)(ws + 327680);
    float4* xyz2q = (float4*)(ws + 331776);
    int*    idx3  = (int*)(ws + 593920);
    float*  w3    = (float*)(ws + 1380352);
    float*  p2t   = (float*)(ws + 2166784);

    prep_transpose_kernel<<<962, 256, 0, stream>>>(
        w0, w1, b0, g0, be0, m0, v0,
        b1, g1, be1, m1, v1,
        xyz2, points2,
        W0h, W1h, sst, xyz2q, p2t);
    knn_kernel<<<dim3(512, 4), 256, 0, stream>>>(xyz1, xyz2q, idx3, w3);
    mlp_kernel<<<dim3(256, 4), 256, 0, stream>>>(points1, pointsb1,
                                                 (const float4*)p2t, idx3, w3,
                                                 (const uint4*)W0h, (const uint4*)W1h,
                                                 sst, out);
}

// Round 10
// 278.932 us; speedup vs baseline: 1.0531x; 1.0531x over previous
//
#include <hip/hip_runtime.h>

#define N1 16384
#define N2 4096
#define CC 128
#define KIN 384
#define HID 256

typedef unsigned short u16;
typedef unsigned int u32;

typedef _Float16 v8h __attribute__((ext_vector_type(8)));
typedef float v4f __attribute__((ext_vector_type(4)));

// ---------- workspace layout (bytes) ----------
// W0h  fp16 256x384           @ 0        (196608)
// W1h  fp16 256x256           @ 196608   (131072)
// sst  fp32 s0,t0,s1,t1 x256  @ 327680   (4096)
// xyz2q float4 B*N2           @ 331776   (262144)
// idx3 int B*N1*3             @ 593920   (786432)
// w3   fp32 B*N1*3            @ 1380352  (786432)
// p2t  fp32 B*N2*C            @ 2166784  (8388608)
// total = 10555392

__device__ __forceinline__ u16 f2h(float f) {
    _Float16 h = (_Float16)f;
    return __builtin_bit_cast(u16, h);
}

// =====================================================================
// Fused prep + transpose (proven, verbatim from the 279.5us config)
// =====================================================================
__global__ __launch_bounds__(256) void prep_transpose_kernel(
    const float* __restrict__ w0, const float* __restrict__ w1,
    const float* __restrict__ b0, const float* __restrict__ g0, const float* __restrict__ be0,
    const float* __restrict__ m0, const float* __restrict__ v0,
    const float* __restrict__ b1, const float* __restrict__ g1, const float* __restrict__ be1,
    const float* __restrict__ m1, const float* __restrict__ v1,
    const float* __restrict__ xyz2, const float* __restrict__ points2,
    u16* __restrict__ W0h, u16* __restrict__ W1h,
    float* __restrict__ sst, float4* __restrict__ xyz2q,
    float* __restrict__ p2t)
{
    __shared__ float tile[64][129];   // 33024 B (transpose blocks only)
    int tid = threadIdx.x;

    if (blockIdx.x < 256) {
        int bid = blockIdx.x;
        int n20 = (bid & 63) * 64;
        int b   = bid >> 6;

        int jr = tid & 63, cr = tid >> 6;
#pragma unroll 8
        for (int it = 0; it < 32; ++it) {
            int ch = it * 4 + cr;
            tile[jr][ch] = points2[((size_t)b * CC + ch) * N2 + n20 + jr];
        }
        __syncthreads();

        int cw = tid & 127, jw0 = tid >> 7;
#pragma unroll 8
        for (int it = 0; it < 32; ++it) {
            int j = it * 2 + jw0;
            p2t[((size_t)b * N2 + n20 + j) * CC + cw] = tile[j][cw];
        }
        return;
    }

    int id = (blockIdx.x - 256) * 256 + tid;
    if (id < 98304) {
        W0h[id] = f2h(w0[id]);
    } else if (id < 163840) {
        int t = id - 98304;
        W1h[t] = f2h(w1[t]);
    } else if (id < 164352) {
        int t = id - 163840;
        int o = t & 255;
        if (t < 256) {
            float s = g0[o] * rsqrtf(v0[o] + 1e-5f);
            sst[o]       = s;
            sst[256 + o] = (b0[o] - m0[o]) * s + be0[o];
        } else {
            float s = g1[o] * rsqrtf(v1[o] + 1e-5f);
            sst[512 + o] = s;
            sst[768 + o] = (b1[o] - m1[o]) * s + be1[o];
        }
    } else if (id < 180736) {
        int t = id - 164352;  // b*N2+n
        float x = xyz2[(size_t)t * 3 + 0];
        float y = xyz2[(size_t)t * 3 + 1];
        float z = xyz2[(size_t)t * 3 + 2];
        xyz2q[t] = make_float4(x, y, z, fmaf(x, x, fmaf(y, y, z * z)));
    }
}

// =====================================================================
// 3-NN + inverse-distance weights (PROVEN 121us kernel, verbatim).
// VALU-issue floor: windowed scans (R2/R3), 4-query amortization (R6),
// and grid splitting (R7) all regressed. ~90% VALUBusy at 51% occupancy.
// =====================================================================
#define BINS(t, cand, D0, D1, D2, I0, I1, I2) do {                    \
    bool c0 = (t) < (D0);                                             \
    bool c1 = (t) < (D1);                                             \
    bool c2 = (t) < (D2);                                             \
    I2 = c1 ? (I1) : (c2 ? (cand) : (I2));   /* old I1 */             \
    I1 = c0 ? (I0) : (c1 ? (cand) : (I1));   /* old I0 */             \
    I0 = c0 ? (cand) : (I0);                                          \
    D2 = __builtin_amdgcn_fmed3f((D1), (t), (D2));  /* old D1 */      \
    D1 = __builtin_amdgcn_fmed3f((D0), (t), (D1));  /* old D0 */      \
    D0 = fminf((t), (D0));                                            \
} while (0)

#define INS3LEX(t, j, D0, D1, D2, I0, I1, I2) do {                    \
    bool lt2 = (t) < (D2) || ((t) == (D2) && (j) < (I2));             \
    bool lt1 = (t) < (D1) || ((t) == (D1) && (j) < (I1));             \
    bool lt0 = (t) < (D0) || ((t) == (D0) && (j) < (I0));             \
    if (lt2) {                                                        \
        if (lt1) {                                                    \
            D2 = (D1); I2 = (I1);                                     \
            if (lt0) { D1 = (D0); I1 = (I0); D0 = (t); I0 = (j); }    \
            else     { D1 = (t); I1 = (j); }                          \
        } else { D2 = (t); I2 = (j); }                                \
    }                                                                 \
} while (0)

#define MERGE_STEP(st, D0, D1, D2, I0, I1, I2) do {                   \
    float e0 = __shfl_xor((D0), (st), 64);                            \
    float e1 = __shfl_xor((D1), (st), 64);                            \
    float e2 = __shfl_xor((D2), (st), 64);                            \
    int   j0 = __shfl_xor((I0), (st), 64);                            \
    int   j1 = __shfl_xor((I1), (st), 64);                            \
    int   j2 = __shfl_xor((I2), (st), 64);                            \
    INS3LEX(e0, j0, D0, D1, D2, I0, I1, I2);                          \
    INS3LEX(e1, j1, D0, D1, D2, I0, I1, I2);                          \
    INS3LEX(e2, j2, D0, D1, D2, I0, I1, I2);                          \
} while (0)

#define KNN_OUT(Q, D0, D1, D2, I0, I1, I2, PP) do {                   \
    float r0 = 1.f / ((D0) + (PP));                                   \
    float r1 = 1.f / ((D1) + (PP));                                   \
    float r2 = 1.f / ((D2) + (PP));                                   \
    float inv = 1.f / (r0 + r1 + r2);                                 \
    size_t o3 = ((size_t)b * N1 + p0 + (Q)) * 3;                      \
    idx3[o3]     = (I0);                                              \
    idx3[o3 + 1] = (I1);                                              \
    idx3[o3 + 2] = (I2);                                              \
    w3[o3]     = r0 * inv;                                            \
    w3[o3 + 1] = r1 * inv;                                            \
    w3[o3 + 2] = r2 * inv;                                            \
} while (0)

__global__ __launch_bounds__(256)
__attribute__((amdgpu_waves_per_eu(8, 8)))
void knn_kernel(
    const float* __restrict__ xyz1, const float4* __restrict__ xyz2q,
    int* __restrict__ idx3, float* __restrict__ w3)
{
    __shared__ float4 slds[1024];   // 16384 B

    int tid = threadIdx.x;
    int b   = blockIdx.y;
    int n0  = blockIdx.x * 32;

    int s  = tid & 15;
    int g  = tid >> 4;
    int p0 = n0 + g * 2;

    size_t pb = ((size_t)b * N1 + p0) * 3;
    float x0 = xyz1[pb + 0], y0 = xyz1[pb + 1], z0 = xyz1[pb + 2];
    float x1 = xyz1[pb + 3], y1 = xyz1[pb + 4], z1 = xyz1[pb + 5];
    float ax0 = -2.f * x0, ay0 = -2.f * y0, az0 = -2.f * z0;
    float ax1 = -2.f * x1, ay1 = -2.f * y1, az1 = -2.f * z1;
    float pp0 = fmaf(x0, x0, fmaf(y0, y0, z0 * z0));
    float pp1 = fmaf(x1, x1, fmaf(y1, y1, z1 * z1));

    float da0 = 1e30f, da1 = 1e30f, da2 = 1e30f;
    float db0 = 1e30f, db1 = 1e30f, db2 = 1e30f;
    int   ia0 = 0, ia1 = 0, ia2 = 0;
    int   ib0 = 0, ib1 = 0, ib2 = 0;

#pragma unroll
    for (int stage = 0; stage < 4; ++stage) {
        int base = stage * 1024;
#pragma unroll
        for (int i = 0; i < 4; ++i)
            slds[tid + i * 256] = xyz2q[(size_t)b * N2 + base + tid + i * 256];
        __syncthreads();

#pragma unroll 4
        for (int k = 0; k < 64; ++k) {
            int c = s + (k << 4);
            float4 v = slds[c];
            int cand = base + c;
            float t0 = fmaf(ax0, v.x, fmaf(ay0, v.y, fmaf(az0, v.z, v.w)));
            float t1 = fmaf(ax1, v.x, fmaf(ay1, v.y, fmaf(az1, v.z, v.w)));
            BINS(t0, cand, da0, da1, da2, ia0, ia1, ia2);
            BINS(t1, cand, db0, db1, db2, ib0, ib1, ib2);
        }
        __syncthreads();
    }

#pragma unroll
    for (int st = 1; st <= 8; st <<= 1) {
        MERGE_STEP(st, da0, da1, da2, ia0, ia1, ia2);
        MERGE_STEP(st, db0, db1, db2, ib0, ib1, ib2);
    }

    if (s == 0) {
        KNN_OUT(0, da0, da1, da2, ia0, ia1, ia2, pp0);
        KNN_OUT(1, db0, db1, db2, ib0, ib1, ib2, pp1);
    }
}

// =====================================================================
// Fused interpolate + concat + MLP(384->256->256, BN+ReLU) + channel max
// 64-POINT TILE, 512-thread (8-wave) blocks -- the PROVEN 279.5us mlp.
// R9 lesson: 4-wave/ot=4 variant regressed (~60 -> ~74us): fewer waves
// per CU + doubled per-wave weight loads hurt latency hiding; LDS-read
// redundancy was only ~5us, never the bottleneck. 8-wave stands.
// =====================================================================
__global__ __launch_bounds__(512, 4)
void mlp_kernel(
    const float* __restrict__ points1, const float* __restrict__ pointsb1,
    const float4* __restrict__ p2t4,
    const int* __restrict__ idx3, const float* __restrict__ w3,
    const uint4* __restrict__ W0v, const uint4* __restrict__ W1v,
    const float* __restrict__ sst, float* __restrict__ out)
{
    __shared__ __align__(16) u16 sx[64 * KIN];   // 49152 B
    __shared__ float sred[8][64];                 // 2048 B
    __shared__ int   s_idx[192];
    __shared__ float s_w[192];

    int tid = threadIdx.x;
    int b   = blockIdx.y;
    int n0  = blockIdx.x * 64;

    if (tid < 192) {
        size_t gi = ((size_t)b * N1 + n0) * 3 + tid;
        s_idx[tid] = idx3[gi];
        s_w[tid]   = w3[gi];
    }

    int pL  = tid & 63;              // point 0..63
    int cg4 = (tid >> 6) * 4;        // row-quad base 0,4,...,28
#pragma unroll
    for (int k = 0; k < 4; ++k) {
        int r4 = cg4 + 32 * k;       // rows 0..124 step 4
        size_t base = ((size_t)b * CC + r4) * N1 + n0 + pL;
        float a0 = points1[base];
        float a1 = points1[base + (size_t)N1];
        float a2 = points1[base + (size_t)2 * N1];
        float a3 = points1[base + (size_t)3 * N1];
        u32 lo = f2h(a0) | ((u32)f2h(a1) << 16);
        u32 hi = f2h(a2) | ((u32)f2h(a3) << 16);
        int chunk = (r4 >> 3) ^ (pL & 7);
        *(uint2*)&sx[pL * KIN + chunk * 8 + (r4 & 7)] = make_uint2(lo, hi);
    }
#pragma unroll
    for (int k = 0; k < 4; ++k) {
        int r4 = cg4 + 32 * k;
        int k4 = 256 + r4;
        size_t base = ((size_t)b * CC + r4) * N1 + n0 + pL;
        float a0 = pointsb1[base];
        float a1 = pointsb1[base + (size_t)N1];
        float a2 = pointsb1[base + (size_t)2 * N1];
        float a3 = pointsb1[base + (size_t)3 * N1];
        u32 lo = f2h(a0) | ((u32)f2h(a1) << 16);
        u32 hi = f2h(a2) | ((u32)f2h(a3) << 16);
        int chunk = (k4 >> 3) ^ (pL & 7);
        *(uint2*)&sx[pL * KIN + chunk * 8 + (k4 & 7)] = make_uint2(lo, hi);
    }
    __syncthreads();   // s_idx/s_w visible for gather

    int c4  = tid & 31;              // channel-quad 0..31
    int pg  = tid >> 5;              // 0..15
    int k4g = 128 + c4 * 4;
#pragma unroll
    for (int k = 0; k < 4; ++k) {
        int p = pg + 16 * k;         // point 0..63
        float w0w = s_w[p * 3 + 0], w1w = s_w[p * 3 + 1], w2w = s_w[p * 3 + 2];
        float4 f0 = p2t4[((size_t)b * N2 + s_idx[p * 3 + 0]) * 32 + c4];
        float4 f1 = p2t4[((size_t)b * N2 + s_idx[p * 3 + 1]) * 32 + c4];
        float4 f2 = p2t4[((size_t)b * N2 + s_idx[p * 3 + 2]) * 32 + c4];
        float e0 = fmaf(w0w, f0.x, fmaf(w1w, f1.x, w2w * f2.x));
        float e1 = fmaf(w0w, f0.y, fmaf(w1w, f1.y, w2w * f2.y));
        float e2 = fmaf(w0w, f0.z, fmaf(w1w, f1.z, w2w * f2.z));
        float e3 = fmaf(w0w, f0.w, fmaf(w1w, f1.w, w2w * f2.w));
        u32 lo = f2h(e0) | ((u32)f2h(e1) << 16);
        u32 hi = f2h(e2) | ((u32)f2h(e3) << 16);
        int chunk = (k4g >> 3) ^ (p & 7);
        *(uint2*)&sx[p * KIN + chunk * 8 + (k4g & 7)] = make_uint2(lo, hi);
    }
    __syncthreads();

    int lane = tid & 63, w = tid >> 6;      // wave w in 0..7: o in [w*32, w*32+32)
    int ml = lane & 15, ql = lane >> 4;     // frag row/col, quad
    int px7 = ml & 7;                       // == p&7 for all pt (p=pt*16+ml)

    // ---------------- GEMM1: h1 = W0 @ x ----------------
    v4f acc1[2][4];
#pragma unroll
    for (int ot = 0; ot < 2; ++ot)
        for (int pt = 0; pt < 4; ++pt)
            acc1[ot][pt] = (v4f){0.f, 0.f, 0.f, 0.f};

#pragma unroll
    for (int s = 0; s < 12; ++s) {
        int kc = s * 4 + ql;
        int pc = (kc ^ px7) * 8;
        v8h bf0 = __builtin_bit_cast(v8h, *(const uint4*)&sx[ml * KIN + pc]);
        v8h bf1 = __builtin_bit_cast(v8h, *(const uint4*)&sx[(16 + ml) * KIN + pc]);
        v8h bf2 = __builtin_bit_cast(v8h, *(const uint4*)&sx[(32 + ml) * KIN + pc]);
        v8h bf3 = __builtin_bit_cast(v8h, *(const uint4*)&sx[(48 + ml) * KIN + pc]);
#pragma unroll
        for (int ot = 0; ot < 2; ++ot) {
            int o = w * 32 + ot * 16 + ml;
            v8h af = __builtin_bit_cast(v8h, W0v[o * 48 + kc]);
            acc1[ot][0] = __builtin_amdgcn_mfma_f32_16x16x32_f16(af, bf0, acc1[ot][0], 0, 0, 0);
            acc1[ot][1] = __builtin_amdgcn_mfma_f32_16x16x32_f16(af, bf1, acc1[ot][1], 0, 0, 0);
            acc1[ot][2] = __builtin_amdgcn_mfma_f32_16x16x32_f16(af, bf2, acc1[ot][2], 0, 0, 0);
            acc1[ot][3] = __builtin_amdgcn_mfma_f32_16x16x32_f16(af, bf3, acc1[ot][3], 0, 0, 0);
        }
    }
    __syncthreads();   // all x reads done before h1 overlays sx

    // epilogue 1: BN+ReLU -> fp16 h1[p][o] (row stride 256, swizzled)
    const float* s0v = sst;
    const float* t0v = sst + 256;
#pragma unroll
    for (int ot = 0; ot < 2; ++ot) {
        int o0 = w * 32 + ot * 16 + ql * 4;
        float sc0 = s0v[o0], sc1 = s0v[o0 + 1], sc2 = s0v[o0 + 2], sc3 = s0v[o0 + 3];
        float sh0 = t0v[o0], sh1 = t0v[o0 + 1], sh2 = t0v[o0 + 2], sh3 = t0v[o0 + 3];
        int chunk = ((o0 >> 3) ^ px7);
#pragma unroll
        for (int pt = 0; pt < 4; ++pt) {
            int p = pt * 16 + ml;
            float z0 = fmaxf(fmaf(acc1[ot][pt][0], sc0, sh0), 0.f);
            float z1 = fmaxf(fmaf(acc1[ot][pt][1], sc1, sh1), 0.f);
            float z2 = fmaxf(fmaf(acc1[ot][pt][2], sc2, sh2), 0.f);
            float z3 = fmaxf(fmaf(acc1[ot][pt][3], sc3, sh3), 0.f);
            u32 lo = f2h(z0) | ((u32)f2h(z1) << 16);
            u32 hi = f2h(z2) | ((u32)f2h(z3) << 16);
            *(uint2*)&sx[p * HID + chunk * 8 + (o0 & 7)] = make_uint2(lo, hi);
        }
    }
    __syncthreads();

    // ---------------- GEMM2: h2 = W1 @ h1 ----------------
    v4f acc2[2][4];
#pragma unroll
    for (int ot = 0; ot < 2; ++ot)
        for (int pt = 0; pt < 4; ++pt)
            acc2[ot][pt] = (v4f){0.f, 0.f, 0.f, 0.f};

#pragma unroll
    for (int s = 0; s < 8; ++s) {
        int kc = s * 4 + ql;
        int pc = (kc ^ px7) * 8;
        v8h bf0 = __builtin_bit_cast(v8h, *(const uint4*)&sx[ml * HID + pc]);
        v8h bf1 = __builtin_bit_cast(v8h, *(const uint4*)&sx[(16 + ml) * HID + pc]);
        v8h bf2 = __builtin_bit_cast(v8h, *(const uint4*)&sx[(32 + ml) * HID + pc]);
        v8h bf3 = __builtin_bit_cast(v8h, *(const uint4*)&sx[(48 + ml) * HID + pc]);
#pragma unroll
        for (int ot = 0; ot < 2; ++ot) {
            int o = w * 32 + ot * 16 + ml;
            v8h af = __builtin_bit_cast(v8h, W1v[o * 32 + kc]);
            acc2[ot][0] = __builtin_amdgcn_mfma_f32_16x16x32_f16(af, bf0, acc2[ot][0], 0, 0, 0);
            acc2[ot][1] = __builtin_amdgcn_mfma_f32_16x16x32_f16(af, bf1, acc2[ot][1], 0, 0, 0);
            acc2[ot][2] = __builtin_amdgcn_mfma_f32_16x16x32_f16(af, bf2, acc2[ot][2], 0, 0, 0);
            acc2[ot][3] = __builtin_amdgcn_mfma_f32_16x16x32_f16(af, bf3, acc2[ot][3], 0, 0, 0);
        }
    }

    // epilogue 2: BN + ReLU (via max with 0) + channel max over this wave's 32 o
    const float* s1v = sst + 512;
    const float* t1v = sst + 768;
    float mx0 = 0.f, mx1 = 0.f, mx2 = 0.f, mx3 = 0.f;   // relu floor = 0
#pragma unroll
    for (int ot = 0; ot < 2; ++ot) {
        int o0 = w * 32 + ot * 16 + ql * 4;
#pragma unroll
        for (int r = 0; r < 4; ++r) {
            float sc = s1v[o0 + r], sh = t1v[o0 + r];
            mx0 = fmaxf(mx0, fmaf(acc2[ot][0][r], sc, sh));
            mx1 = fmaxf(mx1, fmaf(acc2[ot][1][r], sc, sh));
            mx2 = fmaxf(mx2, fmaf(acc2[ot][2][r], sc, sh));
            mx3 = fmaxf(mx3, fmaf(acc2[ot][3][r], sc, sh));
        }
    }
    mx0 = fmaxf(mx0, __shfl_xor(mx0, 16, 64));
    mx0 = fmaxf(mx0, __shfl_xor(mx0, 32, 64));
    mx1 = fmaxf(mx1, __shfl_xor(mx1, 16, 64));
    mx1 = fmaxf(mx1, __shfl_xor(mx1, 32, 64));
    mx2 = fmaxf(mx2, __shfl_xor(mx2, 16, 64));
    mx2 = fmaxf(mx2, __shfl_xor(mx2, 32, 64));
    mx3 = fmaxf(mx3, __shfl_xor(mx3, 16, 64));
    mx3 = fmaxf(mx3, __shfl_xor(mx3, 32, 64));
    if (lane < 16) {
        sred[w][ml]      = mx0;
        sred[w][16 + ml] = mx1;
        sred[w][32 + ml] = mx2;
        sred[w][48 + ml] = mx3;
    }
    __syncthreads();
    if (tid < 64) {
        float m = sred[0][tid];
#pragma unroll
        for (int wv = 1; wv < 8; ++wv)
            m = fmaxf(m, sred[wv][tid]);
        out[(size_t)b * N1 + n0 + tid] = m;
    }
}

// =====================================================================
extern "C" void kernel_launch(void* const* d_in, const int* in_sizes, int n_in,
                              void* d_out, int out_size, void* d_ws, size_t ws_size,
                              hipStream_t stream)
{
    const float* xyz1     = (const float*)d_in[0];
    const float* xyz2     = (const float*)d_in[1];
    const float* points2  = (const float*)d_in[2];
    const float* points1  = (const float*)d_in[3];
    const float* pointsb1 = (const float*)d_in[4];
    const float* w0   = (const float*)d_in[5];
    const float* b0   = (const float*)d_in[6];
    const float* g0   = (const float*)d_in[7];
    const float* be0  = (const float*)d_in[8];
    const float* m0   = (const float*)d_in[9];
    const float* v0   = (const float*)d_in[10];
    const float* w1   = (const float*)d_in[11];
    const float* b1   = (const float*)d_in[12];
    const float* g1   = (const float*)d_in[13];
    const float* be1  = (const float*)d_in[14];
    const float* m1   = (const float*)d_in[15];
    const float* v1   = (const float*)d_in[16];
    float* out = (float*)d_out;

    char* ws = (char*)d_ws;
    u16*    W0h   = (u16*)(ws + 0);
    u16*    W1h   = (u16*)(ws + 196608);
    float*  sst   = (float*)(ws + 327680);
    float4* xyz2q = (float4*)(ws + 331776);
    int*    idx3  = (int*)(ws + 593920);
    float*  w3    = (float*)(ws + 1380352);
    float*  p2t   = (float*)(ws + 2166784);

    prep_transpose_kernel<<<962, 256, 0, stream>>>(
        w0, w1, b0, g0, be0, m0, v0,
        b1, g1, be1, m1, v1,
        xyz2, points2,
        W0h, W1h, sst, xyz2q, p2t);
    knn_kernel<<<dim3(512, 4), 256, 0, stream>>>(xyz1, xyz2q, idx3, w3);
    mlp_kernel<<<dim3(256, 4), 512, 0, stream>>>(points1, pointsb1,
                                                 (const float4*)p2t, idx3, w3,
                                                 (const uint4*)W0h, (const uint4*)W1h,
                                                 sst, out);
}